// Round 7
// baseline (62.329 us; speedup 1.0000x reference)
//
#include <hip/hip_runtime.h>

// Head: FULLY FUSED QKV projection + causal attention, MI355X (gfx950)
// B=512, T=256, C=384, D=64. fp32 in/out, bf16 MFMA compute.
// One block = one batch. 1024 threads = 16 waves, 152 KB LDS, 1 block/CU.
// Phase 1 uses a depth-2 register pipeline: tile t+1's global data is loaded
// one full tile ahead, so the pre-ds_write vmcnt wait is ~free.

typedef short s16x8 __attribute__((ext_vector_type(8)));
typedef float f32x4 __attribute__((ext_vector_type(4)));
typedef float f32x2 __attribute__((ext_vector_type(2)));
typedef unsigned int u32;
typedef unsigned int u32x4 __attribute__((ext_vector_type(4)));
typedef unsigned short u16;
typedef unsigned short u16x4 __attribute__((ext_vector_type(4)));
typedef __bf16 bf16x2 __attribute__((ext_vector_type(2)));

// HW bf16 convert (RNE): lowers to v_cvt_pk_bf16_f32 on gfx950.
__device__ __forceinline__ u32 cvt2(float x, float y) {
  f32x2 v = {x, y};
  bf16x2 b = __builtin_convertvector(v, bf16x2);
  return __builtin_bit_cast(u32, b);
}
__device__ __forceinline__ u16 f2bf(float f) {
  __bf16 b = (__bf16)f;
  return __builtin_bit_cast(u16, b);
}
__device__ __forceinline__ s16x8 pack8(float4 a, float4 b) {
  u32x4 p = {cvt2(a.x, a.y), cvt2(a.z, a.w), cvt2(b.x, b.y), cvt2(b.z, b.w)};
  return __builtin_bit_cast(s16x8, p);
}

#define MFMA16 __builtin_amdgcn_mfma_f32_16x16x32_bf16

// LDS layout (bytes):
//  [0,32768)      xc double buffer (2 x 256x32 bf16 = 2x16KB); phase2: P[16][2KB]
//  [32768,57344)  Wc double buffer (2 x 192x32 bf16 = 2x12KB)
//  [57344,90112)  Q  [256][64] bf16, row-swizzled
//  [90112,122880) K  [256][64] bf16, row-swizzled
//  [122880,155648)V^T[64][256] bf16, round-1 layout
#define XC(b) ((b) * 16384)
#define WC(b) (32768 + (b) * 12288)
#define QS 57344
#define KS 90112
#define VS 122880

// phase-1 per-tile compute: 4 B-frags (x rows) + 3 A-frags (W cols), 12 MFMA
#define P1_COMPUTE(CB)                                                         \
  {                                                                            \
    s16x8 bf_[4], af_[3];                                                      \
    _Pragma("unroll")                                                          \
    for (int bi = 0; bi < 4; ++bi)                                             \
      bf_[bi] = *reinterpret_cast<const s16x8*>(                               \
          smem + XC(CB) + (wr * 64 + bi * 16 + li) * 64 + ((g ^ rswz) << 4));  \
    _Pragma("unroll")                                                          \
    for (int ai = 0; ai < 3; ++ai)                                             \
      af_[ai] = *reinterpret_cast<const s16x8*>(                               \
          smem + WC(CB) + (wc * 48 + ai * 16 + li) * 64 + ((g ^ rswz) << 4));  \
    _Pragma("unroll")                                                          \
    for (int bi = 0; bi < 4; ++bi)                                             \
      _Pragma("unroll")                                                        \
      for (int ai = 0; ai < 3; ++ai)                                           \
        acc[bi][ai] = MFMA16(af_[ai], bf_[bi], acc[bi][ai], 0, 0, 0);          \
  }

#define P1_LOAD(T, XA, XB, WA, WB)                                             \
  {                                                                            \
    const float* px_ = x + xbase + srow * 384 + (T) * 32 + sslot * 8;          \
    XA = *reinterpret_cast<const float4*>(px_);                                \
    XB = *reinterpret_cast<const float4*>(px_ + 4);                            \
    if (do_w) {                                                                \
      WA = *reinterpret_cast<const float4*>(wrp + (T) * 32 + sslot * 8);       \
      WB = *reinterpret_cast<const float4*>(wrp + (T) * 32 + sslot * 8 + 4);   \
    }                                                                          \
  }

#define P1_WRITE(CB, XA, XB, WA, WB)                                           \
  {                                                                            \
    *reinterpret_cast<s16x8*>(                                                 \
        smem + XC(CB) + srow * 64 + ((sslot ^ wswz) << 4)) = pack8(XA, XB);    \
    if (do_w)                                                                  \
      *reinterpret_cast<s16x8*>(                                               \
          smem + WC(CB) + srow * 64 + ((sslot ^ wswz) << 4)) = pack8(WA, WB);  \
  }

__global__ __launch_bounds__(1024) void head_kernel(
    const float* __restrict__ x,
    const float* __restrict__ WQ, const float* __restrict__ WK,
    const float* __restrict__ WV, float* __restrict__ out)
{
  __shared__ char smem[155648];
  const int tid = threadIdx.x;
  const int l  = tid & 63;
  const int w  = tid >> 6;
  const int g  = l >> 4, li = l & 15;
  const int wr = w >> 2, wc = w & 3;     // 4x4 wave grid for phase 1
  const long xbase = (long)blockIdx.x * (256 * 384);
  const long obase = (long)blockIdx.x * (256 * 64);

  // staging coords: 1024 chunks of 8 floats for xc; 768 for Wc
  const int srow  = tid >> 2;          // 0..255
  const int sslot = tid & 3;           // 0..3 (16B slots of a 64B LDS row)
  const bool do_w = (tid < 768);       // waves 0..11 stage W rows 0..191
  const float* wrp = nullptr;
  if (do_w)
    wrp = (srow < 64) ? (WQ + srow * 384)
         : (srow < 128) ? (WK + (srow - 64) * 384)
                        : (WV + (srow - 128) * 384);
  const int wswz = (srow >> 1) & 3;    // write-side swizzle
  const int rswz = (li >> 1) & 3;      // read-side swizzle

  // ---- prologue: stage tile 0 into buf0; prefetch tile 1 into reg-set A ----
  float4 Axa, Axb, Awa = {0,0,0,0}, Awb = {0,0,0,0};
  {
    float4 xa, xb, wa = {0,0,0,0}, wb = {0,0,0,0};
    P1_LOAD(0, xa, xb, wa, wb);
    P1_WRITE(0, xa, xb, wa, wb);
    P1_LOAD(1, Axa, Axb, Awa, Awb);
  }
  __syncthreads();

  f32x4 acc[4][3];   // [bi = 16-row tile][ai = 16-col tile]
#pragma unroll
  for (int bi = 0; bi < 4; ++bi)
#pragma unroll
    for (int ai = 0; ai < 3; ++ai)
      acc[bi][ai] = (f32x4){0.f, 0.f, 0.f, 0.f};

  // ---- phase 1: 12 k-tiles, depth-2 pipeline, one barrier per tile ----
#pragma unroll 1
  for (int it = 0; it < 6; ++it) {
    float4 Bxa, Bxb, Bwa = {0,0,0,0}, Bwb = {0,0,0,0};
    // tile 2*it on buf0: prefetch 2*it+2 -> B, compute, write A(=2*it+1) -> buf1
    if (it < 5) P1_LOAD(it * 2 + 2, Bxa, Bxb, Bwa, Bwb);
    P1_COMPUTE(0);
    P1_WRITE(1, Axa, Axb, Awa, Awb);
    __syncthreads();
    // tile 2*it+1 on buf1: prefetch 2*it+3 -> A, compute, write B -> buf0
    if (it < 5) P1_LOAD(it * 2 + 3, Axa, Axb, Awa, Awb);
    P1_COMPUTE(1);
    if (it < 5) P1_WRITE(0, Bxa, Bxb, Bwa, Bwb);
    __syncthreads();
  }

  // ---- phase-1 epilogue: acc -> Q,K (row-major swz) and V (transposed) ----
  // C/D: lane holds D[n = wc*48 + ai*16 + g*4 + r][row = wr*64 + bi*16 + li]
#pragma unroll
  for (int bi = 0; bi < 4; ++bi) {
    const int row = wr * 64 + bi * 16 + li;
#pragma unroll
    for (int ai = 0; ai < 3; ++ai) {
      const int nb = wc * 48 + ai * 16;
      if (nb < 128) {                   // Q or K: row-major swizzled u16x4
        const int b0 = (nb < 64) ? QS : KS;
        const int d16 = nb & 63;
        const int slot = (d16 >> 3) + (g >> 1);
        u16x4 pk;
        pk[0] = f2bf(acc[bi][ai][0]); pk[1] = f2bf(acc[bi][ai][1]);
        pk[2] = f2bf(acc[bi][ai][2]); pk[3] = f2bf(acc[bi][ai][3]);
        *reinterpret_cast<u16x4*>(
            smem + b0 + row * 128 + ((slot ^ (row & 7)) << 4) + (g & 1) * 8) = pk;
      } else {                          // V: transposed layout
#pragma unroll
        for (int r = 0; r < 4; ++r) {
          int d = nb - 128 + g * 4 + r;
          *reinterpret_cast<u16*>(
              smem + VS + d * 512 + ((row * 2) ^ ((d & 7) << 4))) =
              f2bf(acc[bi][ai][r]);
        }
      }
    }
  }
  __syncthreads();

  // ---- phase 2: causal attention; wave w owns q-tile qt = w ----
  char* Pw = smem + w * 2048;           // overlays retired xc buffers
  const int qt = w;
  s16x8 qf[2];
#pragma unroll
  for (int dk = 0; dk < 2; ++dk) {
    int row = qt * 16 + li;
    qf[dk] = *reinterpret_cast<const s16x8*>(
        smem + QS + row * 128 + (((dk * 4 + g) ^ (row & 7)) << 4));
  }

  f32x4 o[4];
  float m[4], lsum[4];
#pragma unroll
  for (int r = 0; r < 4; ++r) { m[r] = -1e30f; lsum[r] = 0.f; }
#pragma unroll
  for (int nd = 0; nd < 4; ++nd) o[nd] = (f32x4){0.f, 0.f, 0.f, 0.f};

  const int nc = (qt >> 2) + 1;
#pragma unroll 1
  for (int c = 0; c < nc; ++c) {
    // ---- S = Q K^T ----
    f32x4 s[4];
#pragma unroll
    for (int nj = 0; nj < 4; ++nj) s[nj] = (f32x4){0.f, 0.f, 0.f, 0.f};
#pragma unroll
    for (int dk = 0; dk < 2; ++dk) {
#pragma unroll
      for (int nj = 0; nj < 4; ++nj) {
        int rb = c * 64 + nj * 16 + li;
        s16x8 kf = *reinterpret_cast<const s16x8*>(
            smem + KS + rb * 128 + (((dk * 4 + g) ^ (rb & 7)) << 4));
        s[nj] = MFMA16(qf[dk], kf, s[nj], 0, 0, 0);
      }
    }
    const bool last = (c == nc - 1);
    // ---- scale + causal mask ----
#pragma unroll
    for (int nj = 0; nj < 4; ++nj)
#pragma unroll
      for (int r = 0; r < 4; ++r) {
        float v = s[nj][r] * 0.125f;
        if (last && (c * 64 + nj * 16 + li) > (qt * 16 + g * 4 + r)) v = -1e30f;
        s[nj][r] = v;
      }
    // ---- online max ----
    float alpha[4];
#pragma unroll
    for (int r = 0; r < 4; ++r) {
      float pm = fmaxf(fmaxf(s[0][r], s[1][r]), fmaxf(s[2][r], s[3][r]));
      pm = fmaxf(pm, __shfl_xor(pm, 1));
      pm = fmaxf(pm, __shfl_xor(pm, 2));
      pm = fmaxf(pm, __shfl_xor(pm, 4));
      pm = fmaxf(pm, __shfl_xor(pm, 8));
      float mn = fmaxf(m[r], pm);
      alpha[r] = __expf(m[r] - mn);
      m[r] = mn;
    }
    // ---- P = exp(S-m) -> per-wave LDS (swizzled) ----
    float psum[4] = {0.f, 0.f, 0.f, 0.f};
#pragma unroll
    for (int nj = 0; nj < 4; ++nj)
#pragma unroll
      for (int r = 0; r < 4; ++r) {
        float p = __expf(s[nj][r] - m[r]);
        psum[r] += p;
        int rowp = g * 4 + r;
        *reinterpret_cast<u16*>(
            Pw + rowp * 128 + ((nj * 32 + li * 2) ^ ((rowp & 7) << 4))) = f2bf(p);
      }
#pragma unroll
    for (int r = 0; r < 4; ++r) {
      float ps = psum[r];
      ps += __shfl_xor(ps, 1);
      ps += __shfl_xor(ps, 2);
      ps += __shfl_xor(ps, 4);
      ps += __shfl_xor(ps, 8);
      lsum[r] = lsum[r] * alpha[r] + ps;
    }
#pragma unroll
    for (int nd = 0; nd < 4; ++nd)
#pragma unroll
      for (int r = 0; r < 4; ++r) o[nd][r] *= alpha[r];

    __asm__ volatile("s_waitcnt lgkmcnt(0)" ::: "memory");
    // ---- O += P V ----
    s16x8 pa[2];
#pragma unroll
    for (int kk = 0; kk < 2; ++kk)
      pa[kk] = *reinterpret_cast<const s16x8*>(
          Pw + li * 128 + (((kk * 4 + g) ^ (li & 7)) << 4));
#pragma unroll
    for (int nd = 0; nd < 4; ++nd) {
#pragma unroll
      for (int kk = 0; kk < 2; ++kk) {
        int d = nd * 16 + li;
        s16x8 vf = *reinterpret_cast<const s16x8*>(
            smem + VS + d * 512 + ((c * 128 + kk * 64 + g * 16) ^ ((d & 7) << 4)));
        o[nd] = MFMA16(pa[kk], vf, o[nd], 0, 0, 0);
      }
    }
  }
  // ---- output ----
#pragma unroll
  for (int r = 0; r < 4; ++r) lsum[r] = 1.f / lsum[r];
#pragma unroll
  for (int nd = 0; nd < 4; ++nd)
#pragma unroll
    for (int r = 0; r < 4; ++r)
      out[obase + (qt * 16 + g * 4 + r) * 64 + nd * 16 + li] = o[nd][r] * lsum[r];
}

extern "C" void kernel_launch(void* const* d_in, const int* in_sizes, int n_in,
                              void* d_out, int out_size, void* d_ws, size_t ws_size,
                              hipStream_t stream) {
  const float* x  = (const float*)d_in[0];
  const float* WQ = (const float*)d_in[1];
  const float* WK = (const float*)d_in[2];
  const float* WV = (const float*)d_in[3];
  float* out = (float*)d_out;

  head_kernel<<<dim3(512), dim3(1024), 0, stream>>>(x, WQ, WK, WV, out);
}